// Round 4
// baseline (1377.008 us; speedup 1.0000x reference)
//
#include <hip/hip_runtime.h>

// LSTM feedback net: B=16384, T=48 warmup, F=4, UNITS=256, 24 AR steps.
// R15 = R14 (barrier-free wave-dataflow sync) with the aw ring-slot bug fixed:
//  - R14 bug: aw slot = j%3 with per-step ordinal j; 17%3=2 so the ring phase
//    rotated each step -> first 3 K-tiles of every step used the wrong weight
//    tile (deterministic absmax 0.168). Fix: epilogue stages load next-step
//    ords into the slots the next step actually reads: stage 14 (frees aw[2])
//    loads ord 2, stage 15 (frees aw[0]) loads ord 0, stage 16 (frees aw[1])
//    loads ord 1. tt = (j-12)%3 for j>=14; all compile-time after unroll.
//  - Everything else identical to R14: triple-buffered h, per-wave flagH
//    (monotone step counters), flag16 for x/pred feedback, per-wave rotated
//    tile order (2w+j)&15 then 16, pred on waves 0-3 overlapped with waves
//    4-7 running the next step's first 14 tiles.
// Arithmetic is bit-identical to R11 -> absmax must repeat 0.00390625.
// Budget: acc 128 AGPR + VGPR (aw48 + hb16 + c32 + misc~20) <= 256 -> no spill.
// LDS: 3*37888 + flags = 113,712 B (<160K, 1 block/CU, 2 waves/SIMD).

typedef unsigned short u16;
typedef __attribute__((ext_vector_type(8))) short bf16x8;
typedef __attribute__((ext_vector_type(4))) float f32x4;
typedef __attribute__((ext_vector_type(16))) float f32x16;

#define PITCH 296    // hext row pitch, elems (592 B/row)
#define HB 18944     // elems per h buffer (64*296)
#define WARM 48
#define STEPS 71     // 48 warmup + 23 AR cell steps
#define LOG2E  1.442695041f
#define LOG2E2 2.885390082f

__device__ __forceinline__ u16 f2bf(float f) {
    unsigned u = __float_as_uint(f);
    u += 0x7FFFu + ((u >> 16) & 1u);   // round-to-nearest-even
    return (u16)(u >> 16);
}

__device__ __forceinline__ unsigned pk_bf16(float a, float b) {
    unsigned d;
    asm("v_cvt_pk_bf16_f32 %0, %1, %2" : "=v"(d) : "v"(a), "v"(b));
    return d;
}

// producer: drain this wave's LDS writes, then publish flag (lane 0 only)
__device__ __forceinline__ void set_flag(int* f, int v, int lane) {
    asm volatile("s_waitcnt lgkmcnt(0)" ::: "memory");
    if (lane == 0) *(volatile int*)f = v;
}

// consumer: spin until *f >= tgt, then fence so later LDS reads stay later
__device__ __forceinline__ void wait1(const int* f, int tgt) {
    while (*(volatile const int*)f < tgt) {}
    asm volatile("" ::: "memory");
}

__device__ __forceinline__ void wait4(const int* f, int tgt) {
    for (;;) {
        int a = ((volatile const int*)f)[0];
        int b = ((volatile const int*)f)[1];
        int c = ((volatile const int*)f)[2];
        int d = ((volatile const int*)f)[3];
        if (a >= tgt && b >= tgt && c >= tgt && d >= tgt) break;
    }
    asm volatile("" ::: "memory");
}

// ---- prep: 32x32x16 A-fragments of W' (K=272 x N=1024), 17 kt tiles.
// Frag order: idx = kt*32 + wv*4 + g  (g fastest -> imm-offset loads).
// Lane l of a frag holds W'[kt*16+(l>>5)*8+j][256g+32wv+(l&31)], j=0..7.
// K rows: 0..255 Wh, 256..259 Wx, 260 bias. Cols scaled log2e / 2log2e (g).
// wd16: 9 K32-chunks of Wd^T in 16x16x32 A-layout (m=feature), unscaled.
__global__ void prep_weights(const float* __restrict__ Wx,
                             const float* __restrict__ Wh,
                             const float* __restrict__ b,
                             const float* __restrict__ Wd,
                             const float* __restrict__ bd,
                             u16* __restrict__ whext,
                             u16* __restrict__ wdp) {
    int idx = blockIdx.x * 256 + threadIdx.x;   // one thread per 16B chunk
    if (idx < 34816) {                          // 17 kt * 8 wv * 4 g * 64 lanes
        int lane = idx & 63;
        int fr = idx >> 6;
        int g = fr & 3;
        int wv = (fr >> 2) & 7;
        int kt = fr >> 5;
        int k0 = kt * 16 + (lane >> 5) * 8;
        int n = 256 * g + 32 * wv + (lane & 31);
        float sc = (g == 2) ? LOG2E2 : LOG2E;
        u16 v[8];
#pragma unroll
        for (int j = 0; j < 8; ++j) {
            int k = k0 + j;
            float f = 0.0f;
            if (k < 256) f = Wh[k * 1024 + n];
            else if (k < 260) f = Wx[(k - 256) * 1024 + n];
            else if (k == 260) f = b[n];
            v[j] = f2bf(f * sc);
        }
        ushort4* dst = (ushort4*)(whext + (size_t)idx * 8);
        dst[0] = make_ushort4(v[0], v[1], v[2], v[3]);
        dst[1] = make_ushort4(v[4], v[5], v[6], v[7]);
    } else if (idx < 34816 + 576) {             // wd16: 9 chunks x 64 lanes
        int id2 = idx - 34816;
        int lane = id2 & 63;
        int kc = id2 >> 6;
        int m = lane & 15;                      // feature row
        int k0 = kc * 32 + (lane >> 4) * 8;
        u16 v[8];
#pragma unroll
        for (int j = 0; j < 8; ++j) {
            int k = k0 + j;
            float f = 0.0f;
            if (m < 4) {
                if (k < 256) f = Wd[k * 4 + m];
                else if (k == 260) f = bd[m];
            }
            v[j] = f2bf(f);
        }
        ushort4* dst = (ushort4*)(wdp + (size_t)id2 * 8);
        dst[0] = make_ushort4(v[0], v[1], v[2], v[3]);
        dst[1] = make_ushort4(v[4], v[5], v[6], v[7]);
    }
}

// wave base wpw = whext + w*4096B; per kt stride 32768B; per g imm 1024B.
#define WLK(DST, KT) do {                                                     \
    const char* _p = wpw + ((size_t)(KT) << 15);                              \
    DST[0] = *(const bf16x8*)(_p + voffl);                                    \
    DST[1] = *(const bf16x8*)(_p + voffl + 1024);                             \
    DST[2] = *(const bf16x8*)(_p + voffl + 2048);                             \
    DST[3] = *(const bf16x8*)(_p + voffl + 3072);                             \
} while (0)

#define HLD(DST, KT) do {                                                     \
    DST[0] = *(const bf16x8*)&hr[hrow0 + (KT) * 16];                          \
    DST[1] = *(const bf16x8*)&hr[hrow1 + (KT) * 16];                          \
} while (0)

#define MT(WA, HBX)                                                           \
    _Pragma("unroll") for (int m = 0; m < 2; ++m)                             \
    _Pragma("unroll") for (int g = 0; g < 4; ++g)                             \
        acc[m][g] = __builtin_amdgcn_mfma_f32_32x32x16_bf16(                  \
            WA[g], HBX[m], acc[m][g], 0, 0, 0);

__global__ __launch_bounds__(512, 2) void lstm_main(
    const float* __restrict__ x, const u16* __restrict__ whext,
    const u16* __restrict__ wdp, float* __restrict__ out) {
    __shared__ __align__(16) u16 hbuf[3 * HB];   // h triple buffer, 113,664 B
    __shared__ int flagH[8];    // wave w's h slice ready through step flagH[w]
    __shared__ int flag16[4];   // x / pred-feedback ready through step flag16[i]

    const int tid = threadIdx.x;
    const int w = tid >> 6;        // wave 0..7 -> units [32w, 32w+32)
    const int l = tid & 63;
    const int l31 = l & 31;
    const int lh = l >> 5;
    const long long rowBase = (long long)blockIdx.x * 64;

    {   // zero all 3 h buffers (incl. pad cols 261..287 -- stay zero forever)
        int4 z = make_int4(0, 0, 0, 0);
        for (int i = tid; i < 7104; i += 512) ((int4*)hbuf)[i] = z;
        if (tid < 8) flagH[tid] = 0;
        if (tid < 4) flag16[tid] = 0;
    }
    __syncthreads();
    if (tid < 64) {
        hbuf[tid * PITCH + 260] = (u16)0x3F80;            // bias-1 col, buf 0
        hbuf[HB + tid * PITCH + 260] = (u16)0x3F80;       // buf 1
        hbuf[2 * HB + tid * PITCH + 260] = (u16)0x3F80;   // buf 2
        const float4 xv = *(const float4*)(x + (rowBase + tid) * 192);
        uint2* p = (uint2*)&hbuf[tid * PITCH + 256];       // x_0 -> buffer 0
        *p = make_uint2(pk_bf16(xv.x, xv.y), pk_bf16(xv.z, xv.w));
    }
    __syncthreads();   // only block-wide barriers in the kernel (init)

    const char* __restrict__ wpw = (const char*)whext + (size_t)w * 4096;
    const char* __restrict__ dp = (const char*)wdp;
    const int voffl = l * 16;
    const int hrow0 = l31 * PITCH + lh * 8;          // B-frag row, m=0 (elems)
    const int hrow1 = (32 + l31) * PITCH + lh * 8;   // m=1

    f32x16 c[2] = {};      // cell state: m -> batch 32m+l31; reg r -> unit
                           // 32w + (r&3) + 8*(r>>2) + 4*lh
    bf16x8 aw[3][4];       // ring-3 weight frags; within a step ord j -> aw[j%3]
    bf16x8 hb[2][2];       // ring-2 h frags; slot j&1
    // tile order per wave: ord j -> kt = (2w+j)&15 for j<16, kt=16 for j=16
    WLK(aw[0], 2 * w);                 // ord 0 (own)
    WLK(aw[1], 2 * w + 1);             // ord 1 (own)
    WLK(aw[2], (2 * w + 2) & 15);      // ord 2

    int rb = 0;
    for (int step = 0; step < STEPS; ++step) {
        int wb = rb + 1; if (wb == 3) wb = 0;
        const u16* hr = hbuf + rb * HB;      // h_step
        u16* hw = hbuf + wb * HB;            // h_{step+1}

        // wave 0: issue next warmup x load now; consumed after gates
        float4 xv = make_float4(0.f, 0.f, 0.f, 0.f);
        if (w == 0 && step < WARM - 1)
            xv = *(const float4*)(x + (rowBase + l) * 192 + (step + 1) * 4);

        f32x16 acc[2][4] = {};   // [batch-tile m][gate]
        HLD(hb[0], 2 * w);       // own tiles: ordered after own gates writes
        HLD(hb[1], 2 * w + 1);   // by this wave's program order + lgkmcnt

        // 17 stages, no barriers. Stage j: MFMA ord j; flag-gate + HL ord j+2;
        // WL refills the slot freed by this stage's MFMA (aw[j%3]):
        //   j<=13: ord j+3 (slot (j+3)%3 == j%3, same-step ring).
        //   j=14,15,16: NEXT step's ord (j-12)%3 = 2,0,1 -> lands in aw[2],
        //   aw[0], aw[1] = exactly where next step's stages 2,0,1 read them.
        //   (R14 bug: loaded ords 0,1,2 here -> ring phase rotated per step.)
#pragma unroll
        for (int j = 0; j < 17; ++j) {
            MT(aw[j % 3], hb[j & 1]);
            if (j <= 14) {
                const int t2 = j + 2;               // ord to refill (2..16)
                if (t2 == 16) {
                    wait4(flag16, step);            // x_step ready
                    HLD(hb[j & 1], 16);
                } else {
                    if ((t2 & 1) == 0)              // new producer pair
                        wait1(&flagH[(w + t2 / 2) & 7], step);
                    HLD(hb[j & 1], (2 * w + t2) & 15);
                }
            }
            {
                const int tt = (j <= 13) ? (j + 3) : ((j - 12) % 3);
                const int kt3 = (tt < 16) ? ((2 * w + tt) & 15) : 16;
                WLK(aw[j % 3], kt3);
            }
        }

        // gates; lane holds batch 32m+l31, units 32w + (r&3)+8*(r>>2)+4*lh.
        // 7 transcendentals/elem: 5 exp2 + 2 rcp.
#pragma unroll
        for (int m = 0; m < 2; ++m) {
            const int hwrow = (32 * m + l31) * PITCH + 32 * w + 4 * lh;
#pragma unroll
            for (int q = 0; q < 4; ++q) {
                unsigned pk[2];
#pragma unroll
                for (int hp = 0; hp < 2; ++hp) {
                    float h2[2];
#pragma unroll
                    for (int rr = 0; rr < 2; ++rr) {
                        const int r = q * 4 + hp * 2 + rr;
                        float ei = __builtin_amdgcn_exp2f(-acc[m][0][r]);
                        float ef = __builtin_amdgcn_exp2f(-acc[m][1][r]);
                        float eg = __builtin_amdgcn_exp2f(-acc[m][2][r]);
                        float eo = __builtin_amdgcn_exp2f(-acc[m][3][r]);
                        float ai = 1.0f + ei, af = 1.0f + ef;
                        float ag = 1.0f + eg, ao = 1.0f + eo;
                        float P  = ai * ag;
                        float rD = __builtin_amdgcn_rcpf(P * af);
                        float cn = fmaf(c[m][r] * P, rD, (1.0f - eg) * af * rD);
                        c[m][r] = cn;
                        float ec = __builtin_amdgcn_exp2f(-LOG2E2 * cn);
                        float rE = __builtin_amdgcn_rcpf(ao * (1.0f + ec));
                        h2[rr] = (1.0f - ec) * rE;
                    }
                    pk[hp] = pk_bf16(h2[0], h2[1]);
                }
                *(uint2*)&hw[hwrow + 8 * q] = make_uint2(pk[0], pk[1]);
            }
        }
        set_flag(&flagH[w], step + 1, l);   // h_{step+1} slice published

        if (step < WARM - 1) {
            if (w == 0) {   // x_{step+1} (prefetched at step top) -> hw
                uint2* p = (uint2*)&hw[l * PITCH + 256];
                *p = make_uint2(pk_bf16(xv.x, xv.y), pk_bf16(xv.z, xv.w));
                asm volatile("s_waitcnt lgkmcnt(0)" ::: "memory");
                if (l < 4) *(volatile int*)&flag16[l] = step + 1;
            }
        } else if (w < 4) {    // pred on 4 waves; waves 4-7 already moved on
            // need FULL h_{step+1}: wait remaining producers, then fence
            wait4(flagH, step + 1);
            wait4(flagH + 4, step + 1);
            f32x4 pacc = {};
            const int col = l & 15;                     // batch within tile
            const int prow = (16 * w + col) * PITCH + (l >> 4) * 8;
#pragma unroll
            for (int kc = 0; kc < 9; ++kc) {            // K32 chunks 0..8
                bf16x8 hbp = *(const bf16x8*)&hw[prow + kc * 32];
                bf16x8 wap = *(const bf16x8*)(dp + ((size_t)kc * 64 + l) * 16);
                pacc = __builtin_amdgcn_mfma_f32_16x16x32_bf16(wap, hbp, pacc, 0, 0, 0);
            }
            if ((l >> 4) == 0) {   // quad 0: regs 0..3 = features 0..3
                int s = step - (WARM - 1);
                int batch = 16 * w + col;
                *(float4*)&out[((rowBase + batch) * 24 + s) * 4] =
                    make_float4(pacc[0], pacc[1], pacc[2], pacc[3]);
                *(uint2*)&hw[batch * PITCH + 256] =   // feed back as next x_t
                    make_uint2(pk_bf16(pacc[0], pacc[1]), pk_bf16(pacc[2], pacc[3]));
            }
            set_flag(&flag16[w], step + 1, l);
        }
        rb = wb;
    }
}

extern "C" void kernel_launch(void* const* d_in, const int* in_sizes, int n_in,
                              void* d_out, int out_size, void* d_ws, size_t ws_size,
                              hipStream_t stream) {
    const float* x  = (const float*)d_in[0];   // [16384,48,4]
    const float* Wx = (const float*)d_in[1];   // [4,1024]
    const float* Wh = (const float*)d_in[2];   // [256,1024]
    const float* b  = (const float*)d_in[3];   // [1024]
    const float* Wd = (const float*)d_in[4];   // [256,4]
    const float* bd = (const float*)d_in[5];   // [4]
    float* out = (float*)d_out;                // [16384,24,4] fp32

    u16* whext = (u16*)d_ws;                        // 17*32*64*16 = 557056 B
    u16* wdp = (u16*)((char*)d_ws + 557056);        // 9216 B

    prep_weights<<<(34816 + 576 + 255) / 256, 256, 0, stream>>>(Wx, Wh, b, Wd, bd, whext, wdp);
    lstm_main<<<256, 512, 0, stream>>>(x, whext, wdp, out);
}

// Round 5
// 992.196 us; speedup vs baseline: 1.3878x; 1.3878x over previous
//
#include <hip/hip_runtime.h>

// LSTM feedback net: B=16384, T=48 warmup, F=4, UNITS=256, 24 AR steps.
// R16 = R15 (barrier-free wave-dataflow, correct) + SCALARIZED addressing:
//  - R15 post-mortem: passed but 1377us; WRITE_SIZE 710MB (output: 6.3MB) and
//    FETCH 1.5GB = scratch spill/reload + L2 thrash. Cause: rotated tile index
//    kt=(2w+j)&15 is runtime-per-wave, so the 17 weight addresses couldn't
//    fold to base+imm (as R11's literal kt did) -> +~34 VGPR -> spill.
//  - Fix: ws = readfirstlane(w). All tile indices / weight bases / flag
//    addresses become SGPR arithmetic (global_load v,voffl,s[base] form).
//    No VGPR pressure, no address VALU. Everything else identical to R15.
// Arithmetic is bit-identical to R11 -> absmax must repeat 0.00390625.
// Budget: acc 128 AGPR + VGPR (aw48 + hb16 + c32 + misc~25) <= 256, no spill.
// LDS: 3*37888 + flags = 113,712 B (<160K, 1 block/CU, 2 waves/SIMD).

typedef unsigned short u16;
typedef __attribute__((ext_vector_type(8))) short bf16x8;
typedef __attribute__((ext_vector_type(4))) float f32x4;
typedef __attribute__((ext_vector_type(16))) float f32x16;

#define PITCH 296    // hext row pitch, elems (592 B/row)
#define HB 18944     // elems per h buffer (64*296)
#define WARM 48
#define STEPS 71     // 48 warmup + 23 AR cell steps
#define LOG2E  1.442695041f
#define LOG2E2 2.885390082f

__device__ __forceinline__ u16 f2bf(float f) {
    unsigned u = __float_as_uint(f);
    u += 0x7FFFu + ((u >> 16) & 1u);   // round-to-nearest-even
    return (u16)(u >> 16);
}

__device__ __forceinline__ unsigned pk_bf16(float a, float b) {
    unsigned d;
    asm("v_cvt_pk_bf16_f32 %0, %1, %2" : "=v"(d) : "v"(a), "v"(b));
    return d;
}

// producer: drain this wave's LDS writes, then publish flag (lane 0 only)
__device__ __forceinline__ void set_flag(int* f, int v, int lane) {
    asm volatile("s_waitcnt lgkmcnt(0)" ::: "memory");
    if (lane == 0) *(volatile int*)f = v;
}

// consumer: spin until *f >= tgt, then fence so later LDS reads stay later
__device__ __forceinline__ void wait1(const int* f, int tgt) {
    while (*(volatile const int*)f < tgt) {}
    asm volatile("" ::: "memory");
}

__device__ __forceinline__ void wait4(const int* f, int tgt) {
    for (;;) {
        int a = ((volatile const int*)f)[0];
        int b = ((volatile const int*)f)[1];
        int c = ((volatile const int*)f)[2];
        int d = ((volatile const int*)f)[3];
        if (a >= tgt && b >= tgt && c >= tgt && d >= tgt) break;
    }
    asm volatile("" ::: "memory");
}

// ---- prep: 32x32x16 A-fragments of W' (K=272 x N=1024), 17 kt tiles.
// Frag order: idx = kt*32 + wv*4 + g  (g fastest -> imm-offset loads).
// Lane l of a frag holds W'[kt*16+(l>>5)*8+j][256g+32wv+(l&31)], j=0..7.
// K rows: 0..255 Wh, 256..259 Wx, 260 bias. Cols scaled log2e / 2log2e (g).
// wd16: 9 K32-chunks of Wd^T in 16x16x32 A-layout (m=feature), unscaled.
__global__ void prep_weights(const float* __restrict__ Wx,
                             const float* __restrict__ Wh,
                             const float* __restrict__ b,
                             const float* __restrict__ Wd,
                             const float* __restrict__ bd,
                             u16* __restrict__ whext,
                             u16* __restrict__ wdp) {
    int idx = blockIdx.x * 256 + threadIdx.x;   // one thread per 16B chunk
    if (idx < 34816) {                          // 17 kt * 8 wv * 4 g * 64 lanes
        int lane = idx & 63;
        int fr = idx >> 6;
        int g = fr & 3;
        int wv = (fr >> 2) & 7;
        int kt = fr >> 5;
        int k0 = kt * 16 + (lane >> 5) * 8;
        int n = 256 * g + 32 * wv + (lane & 31);
        float sc = (g == 2) ? LOG2E2 : LOG2E;
        u16 v[8];
#pragma unroll
        for (int j = 0; j < 8; ++j) {
            int k = k0 + j;
            float f = 0.0f;
            if (k < 256) f = Wh[k * 1024 + n];
            else if (k < 260) f = Wx[(k - 256) * 1024 + n];
            else if (k == 260) f = b[n];
            v[j] = f2bf(f * sc);
        }
        ushort4* dst = (ushort4*)(whext + (size_t)idx * 8);
        dst[0] = make_ushort4(v[0], v[1], v[2], v[3]);
        dst[1] = make_ushort4(v[4], v[5], v[6], v[7]);
    } else if (idx < 34816 + 576) {             // wd16: 9 chunks x 64 lanes
        int id2 = idx - 34816;
        int lane = id2 & 63;
        int kc = id2 >> 6;
        int m = lane & 15;                      // feature row
        int k0 = kc * 32 + (lane >> 4) * 8;
        u16 v[8];
#pragma unroll
        for (int j = 0; j < 8; ++j) {
            int k = k0 + j;
            float f = 0.0f;
            if (m < 4) {
                if (k < 256) f = Wd[k * 4 + m];
                else if (k == 260) f = bd[m];
            }
            v[j] = f2bf(f);
        }
        ushort4* dst = (ushort4*)(wdp + (size_t)id2 * 8);
        dst[0] = make_ushort4(v[0], v[1], v[2], v[3]);
        dst[1] = make_ushort4(v[4], v[5], v[6], v[7]);
    }
}

// scalar base wbase = whext + ws*4096B; per kt stride 32768B; per g imm 1024B.
// KT is a scalar (ws-derived) expression -> address = SGPR base + voffl.
#define WLK(DST, KT) do {                                                     \
    const char* _p = wbase + ((size_t)(KT) << 15);                            \
    DST[0] = *(const bf16x8*)(_p + voffl);                                    \
    DST[1] = *(const bf16x8*)(_p + voffl + 1024);                             \
    DST[2] = *(const bf16x8*)(_p + voffl + 2048);                             \
    DST[3] = *(const bf16x8*)(_p + voffl + 3072);                             \
} while (0)

#define HLD(DST, KT) do {                                                     \
    DST[0] = *(const bf16x8*)&hr[hrow0 + (KT) * 16];                          \
    DST[1] = *(const bf16x8*)&hr[hrow1 + (KT) * 16];                          \
} while (0)

#define MT(WA, HBX)                                                           \
    _Pragma("unroll") for (int m = 0; m < 2; ++m)                             \
    _Pragma("unroll") for (int g = 0; g < 4; ++g)                             \
        acc[m][g] = __builtin_amdgcn_mfma_f32_32x32x16_bf16(                  \
            WA[g], HBX[m], acc[m][g], 0, 0, 0);

__global__ __launch_bounds__(512, 2) void lstm_main(
    const float* __restrict__ x, const u16* __restrict__ whext,
    const u16* __restrict__ wdp, float* __restrict__ out) {
    __shared__ __align__(16) u16 hbuf[3 * HB];   // h triple buffer, 113,664 B
    __shared__ int flagH[8];    // wave w's h slice ready through step flagH[w]
    __shared__ int flag16[4];   // x / pred-feedback ready through step flag16[i]

    const int tid = threadIdx.x;
    const int w = tid >> 6;        // wave 0..7 -> units [32w, 32w+32)
    const int ws = __builtin_amdgcn_readfirstlane(w);   // wave-uniform -> SGPR
    const int l = tid & 63;
    const int l31 = l & 31;
    const int lh = l >> 5;
    const long long rowBase = (long long)blockIdx.x * 64;

    {   // zero all 3 h buffers (incl. pad cols 261..287 -- stay zero forever)
        int4 z = make_int4(0, 0, 0, 0);
        for (int i = tid; i < 7104; i += 512) ((int4*)hbuf)[i] = z;
        if (tid < 8) flagH[tid] = 0;
        if (tid < 4) flag16[tid] = 0;
    }
    __syncthreads();
    if (tid < 64) {
        hbuf[tid * PITCH + 260] = (u16)0x3F80;            // bias-1 col, buf 0
        hbuf[HB + tid * PITCH + 260] = (u16)0x3F80;       // buf 1
        hbuf[2 * HB + tid * PITCH + 260] = (u16)0x3F80;   // buf 2
        const float4 xv = *(const float4*)(x + (rowBase + tid) * 192);
        uint2* p = (uint2*)&hbuf[tid * PITCH + 256];       // x_0 -> buffer 0
        *p = make_uint2(pk_bf16(xv.x, xv.y), pk_bf16(xv.z, xv.w));
    }
    __syncthreads();   // only block-wide barriers in the kernel (init)

    const char* __restrict__ wbase = (const char*)whext + (size_t)ws * 4096;
    const char* __restrict__ dp = (const char*)wdp;
    const int voffl = l * 16;
    const int hrow0 = l31 * PITCH + lh * 8;          // B-frag row, m=0 (elems)
    const int hrow1 = (32 + l31) * PITCH + lh * 8;   // m=1

    f32x16 c[2] = {};      // cell state: m -> batch 32m+l31; reg r -> unit
                           // 32ws + (r&3) + 8*(r>>2) + 4*lh
    bf16x8 aw[3][4];       // ring-3 weight frags; within a step ord j -> aw[j%3]
    bf16x8 hb[2][2];       // ring-2 h frags; slot j&1
    // tile order per wave: ord j -> kt = (2ws+j)&15 for j<16, kt=16 for j=16
    WLK(aw[0], 2 * ws);                 // ord 0 (own)
    WLK(aw[1], 2 * ws + 1);             // ord 1 (own)
    WLK(aw[2], (2 * ws + 2) & 15);      // ord 2

    int rb = 0;
    for (int step = 0; step < STEPS; ++step) {
        int wb = rb + 1; if (wb == 3) wb = 0;
        const u16* hr = hbuf + rb * HB;      // h_step
        u16* hw = hbuf + wb * HB;            // h_{step+1}

        // wave 0: issue next warmup x load now; consumed after gates
        float4 xv = make_float4(0.f, 0.f, 0.f, 0.f);
        if (ws == 0 && step < WARM - 1)
            xv = *(const float4*)(x + (rowBase + l) * 192 + (step + 1) * 4);

        f32x16 acc[2][4] = {};   // [batch-tile m][gate]
        HLD(hb[0], 2 * ws);      // own tiles: ordered after own gates writes
        HLD(hb[1], 2 * ws + 1);  // by this wave's program order + lgkmcnt

        // 17 stages, no barriers. Stage j: MFMA ord j; flag-gate + HL ord j+2;
        // WL refills the slot freed by this stage's MFMA (aw[j%3]):
        //   j<=13: ord j+3 (slot (j+3)%3 == j%3, same-step ring).
        //   j=14,15,16: NEXT step's ord (j-12)%3 = 2,0,1 -> lands in aw[2],
        //   aw[0], aw[1] = exactly where next step's stages 2,0,1 read them.
#pragma unroll
        for (int j = 0; j < 17; ++j) {
            MT(aw[j % 3], hb[j & 1]);
            if (j <= 14) {
                const int t2 = j + 2;               // ord to refill (2..16)
                if (t2 == 16) {
                    wait4(flag16, step);            // x_step ready
                    HLD(hb[j & 1], 16);
                } else {
                    if ((t2 & 1) == 0)              // new producer pair
                        wait1(&flagH[(ws + t2 / 2) & 7], step);
                    HLD(hb[j & 1], (2 * ws + t2) & 15);
                }
            }
            {
                const int tt = (j <= 13) ? (j + 3) : ((j - 12) % 3);
                const int kt3 = (tt < 16) ? ((2 * ws + tt) & 15) : 16;
                WLK(aw[j % 3], kt3);
            }
        }

        // gates; lane holds batch 32m+l31, units 32ws + (r&3)+8*(r>>2)+4*lh.
        // 7 transcendentals/elem: 5 exp2 + 2 rcp.
#pragma unroll
        for (int m = 0; m < 2; ++m) {
            const int hwrow = (32 * m + l31) * PITCH + 32 * ws + 4 * lh;
#pragma unroll
            for (int q = 0; q < 4; ++q) {
                unsigned pk[2];
#pragma unroll
                for (int hp = 0; hp < 2; ++hp) {
                    float h2[2];
#pragma unroll
                    for (int rr = 0; rr < 2; ++rr) {
                        const int r = q * 4 + hp * 2 + rr;
                        float ei = __builtin_amdgcn_exp2f(-acc[m][0][r]);
                        float ef = __builtin_amdgcn_exp2f(-acc[m][1][r]);
                        float eg = __builtin_amdgcn_exp2f(-acc[m][2][r]);
                        float eo = __builtin_amdgcn_exp2f(-acc[m][3][r]);
                        float ai = 1.0f + ei, af = 1.0f + ef;
                        float ag = 1.0f + eg, ao = 1.0f + eo;
                        float P  = ai * ag;
                        float rD = __builtin_amdgcn_rcpf(P * af);
                        float cn = fmaf(c[m][r] * P, rD, (1.0f - eg) * af * rD);
                        c[m][r] = cn;
                        float ec = __builtin_amdgcn_exp2f(-LOG2E2 * cn);
                        float rE = __builtin_amdgcn_rcpf(ao * (1.0f + ec));
                        h2[rr] = (1.0f - ec) * rE;
                    }
                    pk[hp] = pk_bf16(h2[0], h2[1]);
                }
                *(uint2*)&hw[hwrow + 8 * q] = make_uint2(pk[0], pk[1]);
            }
        }
        set_flag(&flagH[ws], step + 1, l);   // h_{step+1} slice published

        if (step < WARM - 1) {
            if (ws == 0) {   // x_{step+1} (prefetched at step top) -> hw
                uint2* p = (uint2*)&hw[l * PITCH + 256];
                *p = make_uint2(pk_bf16(xv.x, xv.y), pk_bf16(xv.z, xv.w));
                asm volatile("s_waitcnt lgkmcnt(0)" ::: "memory");
                if (l < 4) *(volatile int*)&flag16[l] = step + 1;
            }
        } else if (ws < 4) {   // pred on 4 waves; waves 4-7 already moved on
            // need FULL h_{step+1}: wait remaining producers, then fence
            wait4(flagH, step + 1);
            wait4(flagH + 4, step + 1);
            f32x4 pacc = {};
            const int col = l & 15;                     // batch within tile
            const int prow = (16 * ws + col) * PITCH + (l >> 4) * 8;
#pragma unroll
            for (int kc = 0; kc < 9; ++kc) {            // K32 chunks 0..8
                bf16x8 hbp = *(const bf16x8*)&hw[prow + kc * 32];
                bf16x8 wap = *(const bf16x8*)(dp + ((size_t)kc * 64 + l) * 16);
                pacc = __builtin_amdgcn_mfma_f32_16x16x32_bf16(wap, hbp, pacc, 0, 0, 0);
            }
            if ((l >> 4) == 0) {   // quad 0: regs 0..3 = features 0..3
                int s = step - (WARM - 1);
                int batch = 16 * ws + col;
                *(float4*)&out[((rowBase + batch) * 24 + s) * 4] =
                    make_float4(pacc[0], pacc[1], pacc[2], pacc[3]);
                *(uint2*)&hw[batch * PITCH + 256] =   // feed back as next x_t
                    make_uint2(pk_bf16(pacc[0], pacc[1]), pk_bf16(pacc[2], pacc[3]));
            }
            set_flag(&flag16[ws], step + 1, l);
        }
        rb = wb;
    }
}

extern "C" void kernel_launch(void* const* d_in, const int* in_sizes, int n_in,
                              void* d_out, int out_size, void* d_ws, size_t ws_size,
                              hipStream_t stream) {
    const float* x  = (const float*)d_in[0];   // [16384,48,4]
    const float* Wx = (const float*)d_in[1];   // [4,1024]
    const float* Wh = (const float*)d_in[2];   // [256,1024]
    const float* b  = (const float*)d_in[3];   // [1024]
    const float* Wd = (const float*)d_in[4];   // [256,4]
    const float* bd = (const float*)d_in[5];   // [4]
    float* out = (float*)d_out;                // [16384,24,4] fp32

    u16* whext = (u16*)d_ws;                        // 17*32*64*16 = 557056 B
    u16* wdp = (u16*)((char*)d_ws + 557056);        // 9216 B

    prep_weights<<<(34816 + 576 + 255) / 256, 256, 0, stream>>>(Wx, Wh, b, Wd, bd, whext, wdp);
    lstm_main<<<256, 512, 0, stream>>>(x, whext, wdp, out);
}

// Round 6
// 825.101 us; speedup vs baseline: 1.6689x; 1.2025x over previous
//
#include <hip/hip_runtime.h>

// LSTM feedback net: B=16384, T=48 warmup, F=4, UNITS=256, 24 AR steps.
// R17 = R16 (barrier-free wave-dataflow, scalarized) + register diet to
// kill the residual spill (R16: 325MB scratch writes ~ 9 dw/thread/step):
//  - c state -> LDS (R13-validated, bit-identical, frees 32 VGPR).
//  - h triple buffer -> DOUBLE buffer. Safe proof: before wave w writes
//    h_{s+1} to buf (s+1)&1, its GEMM(s) waited flagH[p]>=s for all 8
//    producers; flagH[p]=s => p finished gates(s-1) => (program order) p
//    finished GEMM(s-1) reads of h_{s-1} = same buffer. No new sync needed.
//  - LDS: 2*37888 + 65536 + flags = 141,360 B < 160K (1 block/CU).
//  - VGPR audit: aw48 + hb16 + xv4 + addr/temps~35 = ~103 < 128 (+acc 128
//    AGPR) -> ~25 regs headroom, spill should vanish entirely.
// Arithmetic is bit-identical to R11 -> absmax must repeat 0.00390625.

typedef unsigned short u16;
typedef __attribute__((ext_vector_type(8))) short bf16x8;
typedef __attribute__((ext_vector_type(4))) float f32x4;
typedef __attribute__((ext_vector_type(16))) float f32x16;

#define PITCH 296    // hext row pitch, elems (592 B/row)
#define HB 18944     // elems per h buffer (64*296)
#define WARM 48
#define STEPS 71     // 48 warmup + 23 AR cell steps
#define LOG2E  1.442695041f
#define LOG2E2 2.885390082f

__device__ __forceinline__ u16 f2bf(float f) {
    unsigned u = __float_as_uint(f);
    u += 0x7FFFu + ((u >> 16) & 1u);   // round-to-nearest-even
    return (u16)(u >> 16);
}

__device__ __forceinline__ unsigned pk_bf16(float a, float b) {
    unsigned d;
    asm("v_cvt_pk_bf16_f32 %0, %1, %2" : "=v"(d) : "v"(a), "v"(b));
    return d;
}

// producer: drain this wave's LDS writes, then publish flag (lane 0 only)
__device__ __forceinline__ void set_flag(int* f, int v, int lane) {
    asm volatile("s_waitcnt lgkmcnt(0)" ::: "memory");
    if (lane == 0) *(volatile int*)f = v;
}

// consumer: spin until *f >= tgt, then fence so later LDS reads stay later
__device__ __forceinline__ void wait1(const int* f, int tgt) {
    while (*(volatile const int*)f < tgt) {}
    asm volatile("" ::: "memory");
}

__device__ __forceinline__ void wait4(const int* f, int tgt) {
    for (;;) {
        int a = ((volatile const int*)f)[0];
        int b = ((volatile const int*)f)[1];
        int c = ((volatile const int*)f)[2];
        int d = ((volatile const int*)f)[3];
        if (a >= tgt && b >= tgt && c >= tgt && d >= tgt) break;
    }
    asm volatile("" ::: "memory");
}

// ---- prep: 32x32x16 A-fragments of W' (K=272 x N=1024), 17 kt tiles.
// Frag order: idx = kt*32 + wv*4 + g  (g fastest -> imm-offset loads).
// Lane l of a frag holds W'[kt*16+(l>>5)*8+j][256g+32wv+(l&31)], j=0..7.
// K rows: 0..255 Wh, 256..259 Wx, 260 bias. Cols scaled log2e / 2log2e (g).
// wd16: 9 K32-chunks of Wd^T in 16x16x32 A-layout (m=feature), unscaled.
__global__ void prep_weights(const float* __restrict__ Wx,
                             const float* __restrict__ Wh,
                             const float* __restrict__ b,
                             const float* __restrict__ Wd,
                             const float* __restrict__ bd,
                             u16* __restrict__ whext,
                             u16* __restrict__ wdp) {
    int idx = blockIdx.x * 256 + threadIdx.x;   // one thread per 16B chunk
    if (idx < 34816) {                          // 17 kt * 8 wv * 4 g * 64 lanes
        int lane = idx & 63;
        int fr = idx >> 6;
        int g = fr & 3;
        int wv = (fr >> 2) & 7;
        int kt = fr >> 5;
        int k0 = kt * 16 + (lane >> 5) * 8;
        int n = 256 * g + 32 * wv + (lane & 31);
        float sc = (g == 2) ? LOG2E2 : LOG2E;
        u16 v[8];
#pragma unroll
        for (int j = 0; j < 8; ++j) {
            int k = k0 + j;
            float f = 0.0f;
            if (k < 256) f = Wh[k * 1024 + n];
            else if (k < 260) f = Wx[(k - 256) * 1024 + n];
            else if (k == 260) f = b[n];
            v[j] = f2bf(f * sc);
        }
        ushort4* dst = (ushort4*)(whext + (size_t)idx * 8);
        dst[0] = make_ushort4(v[0], v[1], v[2], v[3]);
        dst[1] = make_ushort4(v[4], v[5], v[6], v[7]);
    } else if (idx < 34816 + 576) {             // wd16: 9 chunks x 64 lanes
        int id2 = idx - 34816;
        int lane = id2 & 63;
        int kc = id2 >> 6;
        int m = lane & 15;                      // feature row
        int k0 = kc * 32 + (lane >> 4) * 8;
        u16 v[8];
#pragma unroll
        for (int j = 0; j < 8; ++j) {
            int k = k0 + j;
            float f = 0.0f;
            if (m < 4) {
                if (k < 256) f = Wd[k * 4 + m];
                else if (k == 260) f = bd[m];
            }
            v[j] = f2bf(f);
        }
        ushort4* dst = (ushort4*)(wdp + (size_t)id2 * 8);
        dst[0] = make_ushort4(v[0], v[1], v[2], v[3]);
        dst[1] = make_ushort4(v[4], v[5], v[6], v[7]);
    }
}

// scalar base wbase = whext + ws*4096B; per kt stride 32768B; per g imm 1024B.
// KT is a scalar (ws-derived) expression -> address = SGPR base + voffl.
#define WLK(DST, KT) do {                                                     \
    const char* _p = wbase + ((size_t)(KT) << 15);                            \
    DST[0] = *(const bf16x8*)(_p + voffl);                                    \
    DST[1] = *(const bf16x8*)(_p + voffl + 1024);                             \
    DST[2] = *(const bf16x8*)(_p + voffl + 2048);                             \
    DST[3] = *(const bf16x8*)(_p + voffl + 3072);                             \
} while (0)

#define HLD(DST, KT) do {                                                     \
    DST[0] = *(const bf16x8*)&hr[hrow0 + (KT) * 16];                          \
    DST[1] = *(const bf16x8*)&hr[hrow1 + (KT) * 16];                          \
} while (0)

#define MT(WA, HBX)                                                           \
    _Pragma("unroll") for (int m = 0; m < 2; ++m)                             \
    _Pragma("unroll") for (int g = 0; g < 4; ++g)                             \
        acc[m][g] = __builtin_amdgcn_mfma_f32_32x32x16_bf16(                  \
            WA[g], HBX[m], acc[m][g], 0, 0, 0);

__global__ __launch_bounds__(512, 2) void lstm_main(
    const float* __restrict__ x, const u16* __restrict__ whext,
    const u16* __restrict__ wdp, float* __restrict__ out) {
    __shared__ __align__(16) u16 hbuf[2 * HB];     // h double buffer, 75,776 B
    __shared__ __align__(16) float cbuf[16384];    // cell state, 65,536 B
    __shared__ int flagH[8];    // wave w's h slice ready through step flagH[w]
    __shared__ int flag16[4];   // x / pred-feedback ready through step flag16[i]
    // cbuf layout: chunk (m*4+q) in cbuf[chunk*2048 + tid*4 .. +3]
    // -> per-thread f32x4, lane-contiguous 16B (coalesced, conflict-free)

    const int tid = threadIdx.x;
    const int w = tid >> 6;        // wave 0..7 -> units [32w, 32w+32)
    const int ws = __builtin_amdgcn_readfirstlane(w);   // wave-uniform -> SGPR
    const int l = tid & 63;
    const int l31 = l & 31;
    const int lh = l >> 5;
    const long long rowBase = (long long)blockIdx.x * 64;

    {   // zero h buffers (incl. pad cols 261..287) and cell state
        int4 z = make_int4(0, 0, 0, 0);
        for (int i = tid; i < 4736; i += 512) ((int4*)hbuf)[i] = z;
        for (int i = tid; i < 4096; i += 512) ((int4*)cbuf)[i] = z;
        if (tid < 8) flagH[tid] = 0;
        if (tid < 4) flag16[tid] = 0;
    }
    __syncthreads();
    if (tid < 64) {
        hbuf[tid * PITCH + 260] = (u16)0x3F80;        // bias-1 col, buffer 0
        hbuf[HB + tid * PITCH + 260] = (u16)0x3F80;   // and buffer 1
        const float4 xv = *(const float4*)(x + (rowBase + tid) * 192);
        uint2* p = (uint2*)&hbuf[tid * PITCH + 256];   // x_0 -> buffer 0
        *p = make_uint2(pk_bf16(xv.x, xv.y), pk_bf16(xv.z, xv.w));
    }
    __syncthreads();   // only block-wide barriers in the kernel (init)

    const char* __restrict__ wbase = (const char*)whext + (size_t)ws * 4096;
    const char* __restrict__ dp = (const char*)wdp;
    const int voffl = l * 16;
    const int hrow0 = l31 * PITCH + lh * 8;          // B-frag row, m=0 (elems)
    const int hrow1 = (32 + l31) * PITCH + lh * 8;   // m=1

    bf16x8 aw[3][4];       // ring-3 weight frags; within a step ord j -> aw[j%3]
    bf16x8 hb[2][2];       // ring-2 h frags; slot j&1
    // tile order per wave: ord j -> kt = (2ws+j)&15 for j<16, kt=16 for j=16
    WLK(aw[0], 2 * ws);                 // ord 0 (own)
    WLK(aw[1], 2 * ws + 1);             // ord 1 (own)
    WLK(aw[2], (2 * ws + 2) & 15);      // ord 2

    for (int step = 0; step < STEPS; ++step) {
        const u16* hr = hbuf + (step & 1) * HB;      // h_step
        u16* hw = hbuf + ((step & 1) ^ 1) * HB;      // h_{step+1}
        // Double-buffer safety: writes of h_{step+1} hit the buffer that held
        // h_{step-1}; all GEMM(step-1) reads are transitively complete (see
        // header proof) before any wave reaches its gates here.

        // wave 0: issue next warmup x load now; consumed after gates
        float4 xv = make_float4(0.f, 0.f, 0.f, 0.f);
        if (ws == 0 && step < WARM - 1)
            xv = *(const float4*)(x + (rowBase + l) * 192 + (step + 1) * 4);

        f32x16 acc[2][4] = {};   // [batch-tile m][gate]
        HLD(hb[0], 2 * ws);      // own tiles: ordered after own gates writes
        HLD(hb[1], 2 * ws + 1);  // by this wave's program order + lgkmcnt

        // 17 stages, no barriers. Stage j: MFMA ord j; flag-gate + HL ord j+2;
        // WL refills the slot freed by this stage's MFMA (aw[j%3]):
        //   j<=13: ord j+3 (slot (j+3)%3 == j%3, same-step ring).
        //   j=14,15,16: NEXT step's ord (j-12)%3 = 2,0,1 -> lands in aw[2],
        //   aw[0], aw[1] = exactly where next step's stages 2,0,1 read them.
#pragma unroll
        for (int j = 0; j < 17; ++j) {
            MT(aw[j % 3], hb[j & 1]);
            if (j <= 14) {
                const int t2 = j + 2;               // ord to refill (2..16)
                if (t2 == 16) {
                    wait4(flag16, step);            // x_step ready
                    HLD(hb[j & 1], 16);
                } else {
                    if ((t2 & 1) == 0)              // new producer pair
                        wait1(&flagH[(ws + t2 / 2) & 7], step);
                    HLD(hb[j & 1], (2 * ws + t2) & 15);
                }
            }
            {
                const int tt = (j <= 13) ? (j + 3) : ((j - 12) % 3);
                const int kt3 = (tt < 16) ? ((2 * ws + tt) & 15) : 16;
                WLK(aw[j % 3], kt3);
            }
        }

        // gates; lane holds batch 32m+l31, units 32ws + (r&3)+8*(r>>2)+4*lh.
        // 7 transcendentals/elem: 5 exp2 + 2 rcp. c lives in LDS (cbuf).
#pragma unroll
        for (int m = 0; m < 2; ++m) {
            const int hwrow = (32 * m + l31) * PITCH + 32 * ws + 4 * lh;
#pragma unroll
            for (int q = 0; q < 4; ++q) {
                float* cp = cbuf + ((m * 4 + q) << 11) + (tid << 2);
                f32x4 cv = *(const f32x4*)cp;
                f32x4 nv;
                unsigned pk[2];
#pragma unroll
                for (int hp = 0; hp < 2; ++hp) {
                    float h2[2];
#pragma unroll
                    for (int rr = 0; rr < 2; ++rr) {
                        const int r = q * 4 + hp * 2 + rr;
                        const int rc = hp * 2 + rr;
                        float ei = __builtin_amdgcn_exp2f(-acc[m][0][r]);
                        float ef = __builtin_amdgcn_exp2f(-acc[m][1][r]);
                        float eg = __builtin_amdgcn_exp2f(-acc[m][2][r]);
                        float eo = __builtin_amdgcn_exp2f(-acc[m][3][r]);
                        float ai = 1.0f + ei, af = 1.0f + ef;
                        float ag = 1.0f + eg, ao = 1.0f + eo;
                        float P  = ai * ag;
                        float rD = __builtin_amdgcn_rcpf(P * af);
                        float cn = fmaf(cv[rc] * P, rD, (1.0f - eg) * af * rD);
                        nv[rc] = cn;
                        float ec = __builtin_amdgcn_exp2f(-LOG2E2 * cn);
                        float rE = __builtin_amdgcn_rcpf(ao * (1.0f + ec));
                        h2[rr] = (1.0f - ec) * rE;
                    }
                    pk[hp] = pk_bf16(h2[0], h2[1]);
                }
                *(f32x4*)cp = nv;
                *(uint2*)&hw[hwrow + 8 * q] = make_uint2(pk[0], pk[1]);
            }
        }
        set_flag(&flagH[ws], step + 1, l);   // h_{step+1} slice published

        if (step < WARM - 1) {
            if (ws == 0) {   // x_{step+1} (prefetched at step top) -> hw
                uint2* p = (uint2*)&hw[l * PITCH + 256];
                *p = make_uint2(pk_bf16(xv.x, xv.y), pk_bf16(xv.z, xv.w));
                asm volatile("s_waitcnt lgkmcnt(0)" ::: "memory");
                if (l < 4) *(volatile int*)&flag16[l] = step + 1;
            }
        } else if (ws < 4) {   // pred on 4 waves; waves 4-7 already moved on
            // need FULL h_{step+1}: wait remaining producers, then fence
            wait4(flagH, step + 1);
            wait4(flagH + 4, step + 1);
            f32x4 pacc = {};
            const int col = l & 15;                     // batch within tile
            const int prow = (16 * ws + col) * PITCH + (l >> 4) * 8;
#pragma unroll
            for (int kc = 0; kc < 9; ++kc) {            // K32 chunks 0..8
                bf16x8 hbp = *(const bf16x8*)&hw[prow + kc * 32];
                bf16x8 wap = *(const bf16x8*)(dp + ((size_t)kc * 64 + l) * 16);
                pacc = __builtin_amdgcn_mfma_f32_16x16x32_bf16(wap, hbp, pacc, 0, 0, 0);
            }
            if ((l >> 4) == 0) {   // quad 0: regs 0..3 = features 0..3
                int s = step - (WARM - 1);
                int batch = 16 * ws + col;
                *(float4*)&out[((rowBase + batch) * 24 + s) * 4] =
                    make_float4(pacc[0], pacc[1], pacc[2], pacc[3]);
                *(uint2*)&hw[batch * PITCH + 256] =   // feed back as next x_t
                    make_uint2(pk_bf16(pacc[0], pacc[1]), pk_bf16(pacc[2], pacc[3]));
            }
            set_flag(&flag16[ws], step + 1, l);
        }
    }
}

extern "C" void kernel_launch(void* const* d_in, const int* in_sizes, int n_in,
                              void* d_out, int out_size, void* d_ws, size_t ws_size,
                              hipStream_t stream) {
    const float* x  = (const float*)d_in[0];   // [16384,48,4]
    const float* Wx = (const float*)d_in[1];   // [4,1024]
    const float* Wh = (const float*)d_in[2];   // [256,1024]
    const float* b  = (const float*)d_in[3];   // [1024]
    const float* Wd = (const float*)d_in[4];   // [256,4]
    const float* bd = (const float*)d_in[5];   // [4]
    float* out = (float*)d_out;                // [16384,24,4] fp32

    u16* whext = (u16*)d_ws;                        // 17*32*64*16 = 557056 B
    u16* wdp = (u16*)((char*)d_ws + 557056);        // 9216 B

    prep_weights<<<(34816 + 576 + 255) / 256, 256, 0, stream>>>(Wx, Wh, b, Wd, bd, whext, wdp);
    lstm_main<<<256, 512, 0, stream>>>(x, whext, wdp, out);
}

// Round 7
// 742.847 us; speedup vs baseline: 1.8537x; 1.1107x over previous
//
#include <hip/hip_runtime.h>

// LSTM feedback net: B=16384, T=48 warmup, F=4, UNITS=256, 24 AR steps.
// R18 = R11 (best, 744us: phase-locked barriers, c in regs) + pred folded
// into the NEXT step's GEMM phase:
//  - Model (R11..R17 bracket): step = port-paced GEMM (~10K cyc) + gates
//    (~6K) + sync/pred tail (~4.5K). Register wall (acc=128) and CU-port
//    wall (557KB/step) block occupancy/stream moves; the pred tail is the
//    one removable term.
//  - pred(s) only feeds tile-16 x-cols of GEMM(s+1) (consumed at stage 14).
//    So: at step s+1 top (after the barrier), waves 0-3 run pred reading
//    hr's h-part (cols 0-255, disjoint from feedback cols 256-259), write
//    out + feedback into hr, publish flag16 (monotone counters, R17-proven
//    protocol). All waves wait4(flag16) only before the tile-16 h-load.
//    The 9 pred MFMAs hide under port-paced stages 0-13 of waves 4-7.
//  - Second in-loop barrier REMOVED. Last pred (s=23) via one epilogue.
// Arithmetic is bit-identical to R11 -> absmax must repeat 0.00390625.
// Invariant: acc 128 (AGPR) + VGPR (aw48+hb16+c32+misc~16) <= 256, no spill.

typedef unsigned short u16;
typedef __attribute__((ext_vector_type(8))) short bf16x8;
typedef __attribute__((ext_vector_type(4))) float f32x4;
typedef __attribute__((ext_vector_type(16))) float f32x16;

#define PITCH 296    // hext row pitch, elems (592 B/row)
#define HB 18944     // elems per h buffer (64*296)
#define WARM 48
#define STEPS 71     // 48 warmup + 23 AR cell steps
#define LOG2E  1.442695041f
#define LOG2E2 2.885390082f

__device__ __forceinline__ u16 f2bf(float f) {
    unsigned u = __float_as_uint(f);
    u += 0x7FFFu + ((u >> 16) & 1u);   // round-to-nearest-even
    return (u16)(u >> 16);
}

// pack 2 f32 -> 2 bf16 (RNE), one VOP3 instr
__device__ __forceinline__ unsigned pk_bf16(float a, float b) {
    unsigned d;
    asm("v_cvt_pk_bf16_f32 %0, %1, %2" : "=v"(d) : "v"(a), "v"(b));
    return d;
}

// LDS-only barrier: drain LDS ops, NOT vmcnt -> global loads stay in flight.
__device__ __forceinline__ void sync_lds() {
    asm volatile("s_waitcnt lgkmcnt(0)\n\ts_barrier" ::: "memory");
}

// consumer: spin until all 4 flags >= tgt, then fence (R17-proven pattern)
__device__ __forceinline__ void wait4(const int* f, int tgt) {
    for (;;) {
        int a = ((volatile const int*)f)[0];
        int b = ((volatile const int*)f)[1];
        int c = ((volatile const int*)f)[2];
        int d = ((volatile const int*)f)[3];
        if (a >= tgt && b >= tgt && c >= tgt && d >= tgt) break;
    }
    asm volatile("" ::: "memory");
}

// ---- prep: 32x32x16 A-fragments of W' (K=272 x N=1024), 17 kt tiles.
// Frag order: idx = kt*32 + wv*4 + g  (g fastest -> imm-offset loads).
// Lane l of a frag holds W'[kt*16+(l>>5)*8+j][256g+32wv+(l&31)], j=0..7.
// K rows: 0..255 Wh, 256..259 Wx, 260 bias. Cols scaled log2e / 2log2e (g).
// wd16: 9 K32-chunks of Wd^T in 16x16x32 A-layout (m=feature), unscaled.
__global__ void prep_weights(const float* __restrict__ Wx,
                             const float* __restrict__ Wh,
                             const float* __restrict__ b,
                             const float* __restrict__ Wd,
                             const float* __restrict__ bd,
                             u16* __restrict__ whext,
                             u16* __restrict__ wdp) {
    int idx = blockIdx.x * 256 + threadIdx.x;   // one thread per 16B chunk
    if (idx < 34816) {                          // 17 kt * 8 wv * 4 g * 64 lanes
        int lane = idx & 63;
        int fr = idx >> 6;
        int g = fr & 3;
        int wv = (fr >> 2) & 7;
        int kt = fr >> 5;
        int k0 = kt * 16 + (lane >> 5) * 8;
        int n = 256 * g + 32 * wv + (lane & 31);
        float sc = (g == 2) ? LOG2E2 : LOG2E;
        u16 v[8];
#pragma unroll
        for (int j = 0; j < 8; ++j) {
            int k = k0 + j;
            float f = 0.0f;
            if (k < 256) f = Wh[k * 1024 + n];
            else if (k < 260) f = Wx[(k - 256) * 1024 + n];
            else if (k == 260) f = b[n];
            v[j] = f2bf(f * sc);
        }
        ushort4* dst = (ushort4*)(whext + (size_t)idx * 8);
        dst[0] = make_ushort4(v[0], v[1], v[2], v[3]);
        dst[1] = make_ushort4(v[4], v[5], v[6], v[7]);
    } else if (idx < 34816 + 576) {             // wd16: 9 chunks x 64 lanes
        int id2 = idx - 34816;
        int lane = id2 & 63;
        int kc = id2 >> 6;
        int m = lane & 15;                      // feature row
        int k0 = kc * 32 + (lane >> 4) * 8;
        u16 v[8];
#pragma unroll
        for (int j = 0; j < 8; ++j) {
            int k = k0 + j;
            float f = 0.0f;
            if (m < 4) {
                if (k < 256) f = Wd[k * 4 + m];
                else if (k == 260) f = bd[m];
            }
            v[j] = f2bf(f);
        }
        ushort4* dst = (ushort4*)(wdp + (size_t)id2 * 8);
        dst[0] = make_ushort4(v[0], v[1], v[2], v[3]);
        dst[1] = make_ushort4(v[4], v[5], v[6], v[7]);
    }
}

// wave base wpw = whext + w*4096B; per kt stride 32768B; per g imm 1024B.
#define WL(DST, T) do {                                                       \
    const char* _p = wpw + ((size_t)(T) << 15);                               \
    DST[0] = *(const bf16x8*)(_p + voffl);                                    \
    DST[1] = *(const bf16x8*)(_p + voffl + 1024);                             \
    DST[2] = *(const bf16x8*)(_p + voffl + 2048);                             \
    DST[3] = *(const bf16x8*)(_p + voffl + 3072);                             \
} while (0)

#define HL(DST, T) do {                                                       \
    DST[0] = *(const bf16x8*)&hr[hrow0 + (T) * 16];                           \
    DST[1] = *(const bf16x8*)&hr[hrow1 + (T) * 16];                           \
} while (0)

#define MT(WA, HBX)                                                           \
    _Pragma("unroll") for (int m = 0; m < 2; ++m)                             \
    _Pragma("unroll") for (int g = 0; g < 4; ++g)                             \
        acc[m][g] = __builtin_amdgcn_mfma_f32_32x32x16_bf16(                  \
            WA[g], HBX[m], acc[m][g], 0, 0, 0);

// one pipeline stage: consume tile K from (AW,HBX), refill AW<-K+3, HBX<-K+2
#define STG(K, AW, HBX) do { MT(AW, HBX); WL(AW, (K) + 3); HL(HBX, (K) + 2); } while (0)

__global__ __launch_bounds__(512, 2) void lstm_main(
    const float* __restrict__ x, const u16* __restrict__ whext,
    const u16* __restrict__ wdp, float* __restrict__ out) {
    __shared__ __align__(16) u16 hbuf[2 * HB];   // h double buffer
    __shared__ int flag16[4];   // pred-feedback publish counters (monotone)

    const int tid = threadIdx.x;
    const int w = tid >> 6;        // wave 0..7 -> units [32w, 32w+32)
    const int l = tid & 63;
    const int l31 = l & 31;
    const int lh = l >> 5;
    const long long rowBase = (long long)blockIdx.x * 64;

    {   // zero both h buffers (incl. pad cols 261..287 -- stay zero forever)
        int4 z = make_int4(0, 0, 0, 0);
        for (int i = tid; i < 4736; i += 512) ((int4*)hbuf)[i] = z;
        if (tid < 4) flag16[tid] = 0;
    }
    sync_lds();
    if (tid < 64) {
        hbuf[tid * PITCH + 260] = (u16)0x3F80;        // bias-1 col, buffer 0
        hbuf[HB + tid * PITCH + 260] = (u16)0x3F80;   // and buffer 1
        const float4 xv = *(const float4*)(x + (rowBase + tid) * 192);
        uint2* p = (uint2*)&hbuf[tid * PITCH + 256];   // x_0 -> buffer 0
        *p = make_uint2(pk_bf16(xv.x, xv.y), pk_bf16(xv.z, xv.w));
    }

    const char* __restrict__ wpw = (const char*)whext + (size_t)w * 4096;
    const char* __restrict__ dp = (const char*)wdp;
    const int voffl = l * 16;
    const int hrow0 = l31 * PITCH + lh * 8;          // B-frag row, m=0 (elems)
    const int hrow1 = (32 + l31) * PITCH + lh * 8;   // m=1

    f32x16 c[2] = {};      // cell state: m -> batch 32m+l31; reg r -> unit
                           // 32w + (r&3) + 8*(r>>2) + 4*lh
    bf16x8 aw0[4], aw1[4], aw2[4];   // 3-ring: tile k lives in aw[k%3]
    WL(aw0, 0);            // in flight across the first barrier
    WL(aw1, 1);
    WL(aw2, 2);

    for (int step = 0; step < STEPS; ++step) {
        const u16* hr = hbuf + (step & 1) * HB;      // read buffer
        u16* hrw = hbuf + (step & 1) * HB;           // same buffer, writable
        u16* hw = hbuf + ((step & 1) ^ 1) * HB;      // write buffer

        // wave 0: issue next warmup x load now; used ~10us later at step end
        float4 xv = make_float4(0.f, 0.f, 0.f, 0.f);
        if (w == 0 && step < WARM - 1)
            xv = *(const float4*)(x + (rowBase + l) * 192 + (step + 1) * 4);

        sync_lds();   // hr ready; prior reads of hw done; aw0..2 in flight

        // ---- pred for output s = step-WARM, folded into this GEMM phase.
        // Reads hr h-cols (0..255, fully written before the barrier);
        // writes out + feedback x (hr cols 256..259, consumed at stage 14
        // by everyone AFTER wait4(flag16)). Overlaps waves 4-7's stages.
        if (step >= WARM && w < 4) {
            f32x4 pacc = {};
            const int col = l & 15;                     // batch within tile
            const int prow = (16 * w + col) * PITCH + (l >> 4) * 8;
#pragma unroll
            for (int kc = 0; kc < 9; ++kc) {            // K32 chunks 0..8
                bf16x8 hbp = *(const bf16x8*)&hr[prow + kc * 32];
                bf16x8 wap = *(const bf16x8*)(dp + ((size_t)kc * 64 + l) * 16);
                pacc = __builtin_amdgcn_mfma_f32_16x16x32_bf16(wap, hbp, pacc, 0, 0, 0);
            }
            if ((l >> 4) == 0) {   // quad 0: regs 0..3 = features 0..3
                int s = step - WARM;
                int batch = 16 * w + col;
                *(float4*)&out[((rowBase + batch) * 24 + s) * 4] =
                    make_float4(pacc[0], pacc[1], pacc[2], pacc[3]);
                *(uint2*)&hrw[batch * PITCH + 256] =   // feedback as x_step
                    make_uint2(pk_bf16(pacc[0], pacc[1]), pk_bf16(pacc[2], pacc[3]));
            }
            asm volatile("s_waitcnt lgkmcnt(0)" ::: "memory");
            if (l == 0) *(volatile int*)&flag16[w] = step - WARM + 1;
        }

        f32x16 acc[2][4] = {};   // [batch-tile m][gate]
        bf16x8 hb0[2], hb1[2];   // 2-ring: tile k lives in hb[k&1]
        HL(hb0, 0);
        HL(hb1, 1);

        // 17 K-tiles. Stage k: MT(aw[k%3], hb[k&1]); WL<-k+3; HL<-k+2.
        STG(0, aw0, hb0);
        STG(1, aw1, hb1);
#pragma unroll 1
        for (int k = 2; k < 14; k += 6) {   // k = 2..13, fixed slot pattern
            STG(k + 0, aw2, hb0);
            STG(k + 1, aw0, hb1);
            STG(k + 2, aw1, hb0);
            STG(k + 3, aw2, hb1);
            STG(k + 4, aw0, hb0);
            STG(k + 5, aw1, hb1);
        }
        MT(aw2, hb0); WL(aw2, 2);
        if (step >= WARM) wait4(flag16, step - WARM + 1);   // x_step published?
        HL(hb0, 16);                             // tile 14; prestage next-2
        MT(aw0, hb1); WL(aw0, 0);                // tile 15; prestage next-0
        MT(aw1, hb0); WL(aw1, 1);                // tile 16; prestage next-1
        // aw0..2 now hold NEXT step's tiles 0..2, flying over gates+barrier

        // gates; lane holds batch 32m+l31, units 32w + (r&3)+8*(r>>2)+4*lh.
        // 7 transcendentals/elem: 5 exp2 + 2 rcp.
#pragma unroll
        for (int m = 0; m < 2; ++m) {
            const int hwrow = (32 * m + l31) * PITCH + 32 * w + 4 * lh;
#pragma unroll
            for (int q = 0; q < 4; ++q) {
                unsigned pk[2];
#pragma unroll
                for (int hp = 0; hp < 2; ++hp) {
                    float h2[2];
#pragma unroll
                    for (int rr = 0; rr < 2; ++rr) {
                        const int r = q * 4 + hp * 2 + rr;
                        float ei = __builtin_amdgcn_exp2f(-acc[m][0][r]);
                        float ef = __builtin_amdgcn_exp2f(-acc[m][1][r]);
                        float eg = __builtin_amdgcn_exp2f(-acc[m][2][r]);
                        float eo = __builtin_amdgcn_exp2f(-acc[m][3][r]);
                        float ai = 1.0f + ei, af = 1.0f + ef;
                        float ag = 1.0f + eg, ao = 1.0f + eo;
                        float P  = ai * ag;
                        float rD = __builtin_amdgcn_rcpf(P * af);
                        float cn = fmaf(c[m][r] * P, rD, (1.0f - eg) * af * rD);
                        c[m][r] = cn;
                        float ec = __builtin_amdgcn_exp2f(-LOG2E2 * cn);
                        float rE = __builtin_amdgcn_rcpf(ao * (1.0f + ec));
                        h2[rr] = (1.0f - ec) * rE;
                    }
                    pk[hp] = pk_bf16(h2[0], h2[1]);
                }
                *(uint2*)&hw[hwrow + 8 * q] = make_uint2(pk[0], pk[1]);
            }
        }

        if (step < WARM - 1) {
            if (w == 0) {   // x_{step+1} (prefetched at step top) -> hw
                uint2* p = (uint2*)&hw[l * PITCH + 256];
                *p = make_uint2(pk_bf16(xv.x, xv.y), pk_bf16(xv.z, xv.w));
            }
        }
        // AR steps: no second barrier, no serial pred tail -- pred for this
        // step's h runs at the TOP of the next iteration, overlapped.
    }

    // ---- epilogue: last prediction (s = 23) from h_71 (no feedback needed)
    sync_lds();
    if (w < 4) {
        const u16* hf = hbuf + (((STEPS - 1) & 1) ^ 1) * HB;
        f32x4 pacc = {};
        const int col = l & 15;
        const int prow = (16 * w + col) * PITCH + (l >> 4) * 8;
#pragma unroll
        for (int kc = 0; kc < 9; ++kc) {
            bf16x8 hbp = *(const bf16x8*)&hf[prow + kc * 32];
            bf16x8 wap = *(const bf16x8*)(dp + ((size_t)kc * 64 + l) * 16);
            pacc = __builtin_amdgcn_mfma_f32_16x16x32_bf16(wap, hbp, pacc, 0, 0, 0);
        }
        if ((l >> 4) == 0) {
            int batch = 16 * w + col;
            *(float4*)&out[((rowBase + batch) * 24 + 23) * 4] =
                make_float4(pacc[0], pacc[1], pacc[2], pacc[3]);
        }
    }
}

extern "C" void kernel_launch(void* const* d_in, const int* in_sizes, int n_in,
                              void* d_out, int out_size, void* d_ws, size_t ws_size,
                              hipStream_t stream) {
    const float* x  = (const float*)d_in[0];   // [16384,48,4]
    const float* Wx = (const float*)d_in[1];   // [4,1024]
    const float* Wh = (const float*)d_in[2];   // [256,1024]
    const float* b  = (const float*)d_in[3];   // [1024]
    const float* Wd = (const float*)d_in[4];   // [256,4]
    const float* bd = (const float*)d_in[5];   // [4]
    float* out = (float*)d_out;                // [16384,24,4] fp32

    u16* whext = (u16*)d_ws;                        // 17*32*64*16 = 557056 B
    u16* wdp = (u16*)((char*)d_ws + 557056);        // 9216 B

    prep_weights<<<(34816 + 576 + 255) / 256, 256, 0, stream>>>(Wx, Wh, b, Wd, bd, whext, wdp);
    lstm_main<<<256, 512, 0, stream>>>(x, whext, wdp, out);
}